// Round 1
// baseline (699.750 us; speedup 1.0000x reference)
//
#include <hip/hip_runtime.h>
#include <math.h>

#define NEGV (-999999.0f)
constexpr int Bc = 8, Nc = 2048, Dc = 256;
constexpr int BN = Bc * Nc; // 16384

__device__ __forceinline__ float sigmoidf_(float x) { return 1.0f / (1.0f + expf(-x)); }

// ---------------- pack Bmat[256][512] = [ W | Hw^T ] ----------------
__global__ void pack_b_kernel(const float* __restrict__ W, const float* __restrict__ Hw,
                              float* __restrict__ Bm) {
    int idx = blockIdx.x * 256 + threadIdx.x; // 0..131071
    int k = idx >> 9, o = idx & 511;
    float v = (o < 256) ? W[k * 256 + o] : Hw[(o - 256) * 256 + k];
    Bm[idx] = v;
}

// ---------------- C = A(16384x256) @ Bm(256x512); h | gate epilogue ----------------
__global__ __launch_bounds__(256) void gemm_kernel(const float* __restrict__ A,
                                                   const float* __restrict__ Bm,
                                                   const float* __restrict__ Hb,
                                                   float* __restrict__ h,
                                                   float* __restrict__ gate) {
    __shared__ __align__(16) float As[32][64]; // [k][m]
    __shared__ __align__(16) float Bs[32][64]; // [k][n]
    const int tid = threadIdx.x;
    const int tx = tid & 15, ty = tid >> 4;
    const int m0 = blockIdx.x * 64, n0 = blockIdx.y * 64;
    float acc[4][4] = {};
    for (int k0 = 0; k0 < 256; k0 += 32) {
#pragma unroll
        for (int p = 0; p < 2; ++p) { // A tile 64x32, transposed into LDS
            int f4 = tid + p * 256;
            int m = f4 >> 3, kq = (f4 & 7) * 4;
            float4 v = *(const float4*)(A + (size_t)(m0 + m) * 256 + k0 + kq);
            As[kq + 0][m] = v.x; As[kq + 1][m] = v.y; As[kq + 2][m] = v.z; As[kq + 3][m] = v.w;
        }
#pragma unroll
        for (int p = 0; p < 2; ++p) { // B tile 32x64
            int f4 = tid + p * 256;
            int k = f4 >> 4, nq = (f4 & 15) * 4;
            *(float4*)&Bs[k][nq] = *(const float4*)(Bm + (size_t)(k0 + k) * 512 + n0 + nq);
        }
        __syncthreads();
#pragma unroll
        for (int k = 0; k < 32; ++k) {
            float4 a4 = *(const float4*)&As[k][ty * 4];
            float4 b4 = *(const float4*)&Bs[k][tx * 4];
            float av[4] = {a4.x, a4.y, a4.z, a4.w};
            float bv[4] = {b4.x, b4.y, b4.z, b4.w};
#pragma unroll
            for (int i = 0; i < 4; ++i)
#pragma unroll
                for (int j = 0; j < 4; ++j) acc[i][j] = fmaf(av[i], bv[j], acc[i][j]);
        }
        __syncthreads();
    }
    const int o0 = n0 + tx * 4;
#pragma unroll
    for (int i = 0; i < 4; ++i) {
        int m = m0 + ty * 4 + i;
        if (o0 < 256) {
            float4 v = {acc[i][0], acc[i][1], acc[i][2], acc[i][3]};
            *(float4*)(h + (size_t)m * 256 + o0) = v;
        } else {
            int o = o0 - 256;
            float4 v;
            v.x = sigmoidf_(acc[i][0] + Hb[o + 0]);
            v.y = sigmoidf_(acc[i][1] + Hb[o + 1]);
            v.z = sigmoidf_(acc[i][2] + Hb[o + 2]);
            v.w = sigmoidf_(acc[i][3] + Hb[o + 3]);
            *(float4*)(gate + (size_t)m * 256 + o) = v;
        }
    }
}

// ---------------- per-row a_src/a_dst: one wave per row ----------------
__global__ __launch_bounds__(256) void asrc_kernel(const float* __restrict__ h,
                                                   const float* __restrict__ Ws,
                                                   float* __restrict__ a_src,
                                                   float* __restrict__ a_dst) {
    const int row = blockIdx.x * 4 + (threadIdx.x >> 6);
    const int lane = threadIdx.x & 63;
    float4 h4 = ((const float4*)(h + (size_t)row * 256))[lane];
    float4 ws = ((const float4*)Ws)[lane];
    float4 wd = ((const float4*)(Ws + 256))[lane];
    float s1 = h4.x * ws.x + h4.y * ws.y + h4.z * ws.z + h4.w * ws.w;
    float s2 = h4.x * wd.x + h4.y * wd.y + h4.z * wd.z + h4.w * wd.w;
#pragma unroll
    for (int m = 32; m >= 1; m >>= 1) {
        s1 += __shfl_xor(s1, m, 64);
        s2 += __shfl_xor(s2, m, 64);
    }
    if (lane == 0) { a_src[row] = s1; a_dst[row] = s2; }
}

// ---------------- per-batch sum over rows of h (raw sums; /N at use) ----------------
__global__ __launch_bounds__(256) void mean_kernel(const float* __restrict__ h,
                                                   float* __restrict__ mean_h) {
    const int blk = blockIdx.x;        // B*32 blocks
    const int b = blk >> 5, part = blk & 31;
    const int d = threadIdx.x;
    float sum = 0.f;
    const float* base = h + ((size_t)b * Nc + part * 64) * 256 + d;
#pragma unroll 4
    for (int r = 0; r < 64; ++r) sum += base[(size_t)r * 256];
    atomicAdd(&mean_h[b * 256 + d], sum);
}

// ---------------- fused attention: scores -> I_A write -> online softmax -> P@h ----------------
__global__ __launch_bounds__(256) void attn_kernel(
    const int* __restrict__ adj, const float* __restrict__ h,
    const float* __restrict__ gate, const float* __restrict__ feat,
    const float* __restrict__ a_src, const float* __restrict__ a_dst,
    const float* __restrict__ bvec, const float* __restrict__ bs_p,
    const float* __restrict__ mean_h, float* __restrict__ out1,
    float* __restrict__ out2) {
    __shared__ __align__(16) float sh_h[32][256]; // 32 KB h tile
    __shared__ float sc[32][32];
    __shared__ float pt[32][32];
    __shared__ float m_lds[32], scale_lds[32], tsum_lds[32], sh_asrc[32];

    const int bx = blockIdx.x;
    const int b = bx & 7;                       // batch -> XCD affinity
    const int k = bx >> 3;
    const int ib = (k & 1) ? (63 - (k >> 1)) : (k >> 1); // long+short pairing
    const int i0 = ib * 32;
    const int tid = threadIdx.x;
    const int lane = tid & 63;
    const int w = tid >> 6;
    const float bsv = bs_p[0];

    if (tid < 32) {
        m_lds[tid] = -INFINITY;
        sh_asrc[tid] = a_src[b * Nc + i0 + tid];
    }
    float s[8];
    float4 acc[8];
#pragma unroll
    for (int r = 0; r < 8; ++r) { s[r] = 0.f; acc[r] = make_float4(0.f, 0.f, 0.f, 0.f); }

    const int jj_ = tid & 31;
    const int r0 = tid >> 5;
    const int T = i0 / 32 + 1;

    for (int t = 0; t < T; ++t) {
        const int j0 = t * 32;
        if (t > 0) __syncthreads();
        { // stage h tile (32 rows x 256)
            const float4* src = (const float4*)(h + ((size_t)b * Nc + j0) * 256);
            float4* dst = (float4*)&sh_h[0][0];
#pragma unroll
            for (int p = 0; p < 8; ++p) dst[tid + p * 256] = src[tid + p * 256];
        }
        { // phase 1: scores + I_A write
            const int j = j0 + jj_;
            const float adstj = a_dst[b * Nc + j];
#pragma unroll
            for (int q = 0; q < 4; ++q) {
                const int r = r0 + 8 * q;
                const int i = i0 + r;
                const int av = adj[((size_t)b * Nc + i) * Nc + j];
                float IA;
                if (j > i) IA = 0.f;
                else if (j == i) IA = 1.f;
                else IA = -sigmoidf_(sh_asrc[r] + adstj + bsv);
                out2[((size_t)b * Nc + i) * Nc + j] = IA;
                const bool allowed = (j <= i) && (av == 1);
                sc[r][jj_] = allowed ? IA : NEGV;
            }
        }
        __syncthreads();
        { // phase 1b: per-row tile max / exp / sum (half-wave per row)
#pragma unroll
            for (int q = 0; q < 4; ++q) {
                const int r = r0 + 8 * q;
                float v = sc[r][jj_];
                float mx = v;
#pragma unroll
                for (int d = 16; d >= 1; d >>= 1) mx = fmaxf(mx, __shfl_xor(mx, d, 32));
                const float mold = m_lds[r];
                const float mnew = fmaxf(mold, mx);
                const float p = expf(v - mnew);
                pt[r][jj_] = p;
                float ts = p;
#pragma unroll
                for (int d = 16; d >= 1; d >>= 1) ts += __shfl_xor(ts, d, 32);
                if (jj_ == 0) {
                    scale_lds[r] = expf(mold - mnew);
                    tsum_lds[r] = ts;
                    m_lds[r] = mnew;
                }
            }
        }
        __syncthreads();
        { // phase 2: rescale + accumulate P@h (wave w owns rows w*8..w*8+7)
#pragma unroll
            for (int rr = 0; rr < 8; ++rr) {
                const int r = w * 8 + rr;
                const float scl = scale_lds[r];
                s[rr] = s[rr] * scl + tsum_lds[r];
                acc[rr].x *= scl; acc[rr].y *= scl; acc[rr].z *= scl; acc[rr].w *= scl;
            }
            const float4* sh4 = (const float4*)&sh_h[0][0];
            for (int jj = 0; jj < 32; ++jj) {
                const float4 h4 = sh4[jj * 64 + lane];
#pragma unroll
                for (int rr = 0; rr < 8; ++rr) {
                    const float p = pt[w * 8 + rr][jj];
                    acc[rr].x = fmaf(p, h4.x, acc[rr].x);
                    acc[rr].y = fmaf(p, h4.y, acc[rr].y);
                    acc[rr].z = fmaf(p, h4.z, acc[rr].z);
                    acc[rr].w = fmaf(p, h4.w, acc[rr].w);
                }
            }
        }
    }
    { // zero-fill upper-triangle tail of I_A_raw
        const int tail4 = (i0 + 32) >> 2;
        const float4 z = make_float4(0.f, 0.f, 0.f, 0.f);
        for (int r = 0; r < 32; ++r) {
            float4* row = (float4*)(out2 + ((size_t)b * Nc + i0 + r) * Nc);
            for (int j4 = tail4 + tid; j4 < Nc / 4; j4 += 256) row[j4] = z;
        }
    }
    { // epilogue: normalize (or mean fallback), +b, ELU, gate mix
        const float4 b4 = ((const float4*)bvec)[lane];
#pragma unroll
        for (int rr = 0; rr < 8; ++rr) {
            const int r = w * 8 + rr;
            const size_t g = (size_t)b * Nc + i0 + r;
            float4 v;
            if (m_lds[r] < -1e5f) { // fully-masked row: softmax uniform over ALL N cols
                float4 mh = ((const float4*)(mean_h + b * 256))[lane];
                const float inv = 1.0f / Nc;
                v.x = mh.x * inv; v.y = mh.y * inv; v.z = mh.z * inv; v.w = mh.w * inv;
            } else {
                const float inv = 1.0f / s[rr];
                v.x = acc[rr].x * inv; v.y = acc[rr].y * inv;
                v.z = acc[rr].z * inv; v.w = acc[rr].w * inv;
            }
            v.x += b4.x; v.y += b4.y; v.z += b4.z; v.w += b4.w;
            v.x = v.x > 0.f ? v.x : expf(v.x) - 1.f;
            v.y = v.y > 0.f ? v.y : expf(v.y) - 1.f;
            v.z = v.z > 0.f ? v.z : expf(v.z) - 1.f;
            v.w = v.w > 0.f ? v.w : expf(v.w) - 1.f;
            const float4 g4 = ((const float4*)(gate + g * 256))[lane];
            const float4 f4 = ((const float4*)(feat + g * 256))[lane];
            float4 o;
            o.x = g4.x * v.x + (1.f - g4.x) * f4.x;
            o.y = g4.y * v.y + (1.f - g4.y) * f4.y;
            o.z = g4.z * v.z + (1.f - g4.z) * f4.z;
            o.w = g4.w * v.w + (1.f - g4.w) * f4.w;
            ((float4*)(out1 + g * 256))[lane] = o;
        }
    }
}

extern "C" void kernel_launch(void* const* d_in, const int* in_sizes, int n_in,
                              void* d_out, int out_size, void* d_ws, size_t ws_size,
                              hipStream_t stream) {
    const float* feat = (const float*)d_in[0];
    const int* adj = (const int*)d_in[1];
    const float* W = (const float*)d_in[2];
    const float* bvec = (const float*)d_in[3];
    const float* Ws = (const float*)d_in[4];
    const float* bs = (const float*)d_in[5];
    const float* Hw = (const float*)d_in[6];
    const float* Hb = (const float*)d_in[7];

    float* ws = (float*)d_ws;
    float* Bm = ws;                       // 131072
    float* h = Bm + 131072;               // 4194304
    float* gate = h + 4194304;            // 4194304
    float* a_src = gate + 4194304;        // 16384
    float* a_dst = a_src + 16384;         // 16384
    float* mean_h = a_dst + 16384;        // 2048

    float* out1 = (float*)d_out;
    float* out2 = out1 + (size_t)Bc * Nc * 256;

    hipLaunchKernelGGL(pack_b_kernel, dim3(512), dim3(256), 0, stream, W, Hw, Bm);
    hipLaunchKernelGGL(gemm_kernel, dim3(256, 8), dim3(256), 0, stream, feat, Bm, Hb, h, gate);
    hipLaunchKernelGGL(asrc_kernel, dim3(4096), dim3(256), 0, stream, h, Ws, a_src, a_dst);
    hipMemsetAsync(mean_h, 0, 2048 * sizeof(float), stream);
    hipLaunchKernelGGL(mean_kernel, dim3(256), dim3(256), 0, stream, h, mean_h);
    hipLaunchKernelGGL(attn_kernel, dim3(512), dim3(256), 0, stream,
                       adj, h, gate, feat, a_src, a_dst, bvec, bs, mean_h, out1, out2);
}

// Round 3
// 617.759 us; speedup vs baseline: 1.1327x; 1.1327x over previous
//
#include <hip/hip_runtime.h>
#include <math.h>

#define NEGV (-999999.0f)
constexpr int Bc = 8, Nc = 2048, Dc = 256;
constexpr int BN = Bc * Nc; // 16384

__device__ __forceinline__ float sigmoidf_(float x) { return 1.0f / (1.0f + expf(-x)); }

// ---------------- pack Bmat[256][512] = [ W | Hw^T ] ----------------
__global__ void pack_b_kernel(const float* __restrict__ W, const float* __restrict__ Hw,
                              float* __restrict__ Bm) {
    int idx = blockIdx.x * 256 + threadIdx.x; // 0..131071
    int k = idx >> 9, o = idx & 511;
    float v = (o < 256) ? W[k * 256 + o] : Hw[(o - 256) * 256 + k];
    Bm[idx] = v;
}

// ---------------- C = A(16384x256) @ Bm(256x512), 128x128 tile, 8x8 micro ----------------
__global__ __launch_bounds__(256) void gemm128_kernel(const float* __restrict__ A,
                                                      const float* __restrict__ Bm,
                                                      const float* __restrict__ Hb,
                                                      float* __restrict__ h,
                                                      float* __restrict__ gate) {
    __shared__ __align__(16) float As[32][128]; // [k][m]
    __shared__ __align__(16) float Bs[32][128]; // [k][n]
    const int tid = threadIdx.x;
    const int tx = tid & 15, ty = tid >> 4;
    const int m0 = blockIdx.x * 128, n0 = blockIdx.y * 128;
    float acc[2][2][4][4] = {}; // [mh][nh][mi][ni]
    for (int k0 = 0; k0 < 256; k0 += 32) {
        if (k0) __syncthreads();
#pragma unroll
        for (int p = 0; p < 4; ++p) { // A tile 128x32 transposed into LDS
            int f4 = tid + p * 256;
            int m = f4 >> 3, kq = (f4 & 7) * 4;
            float4 v = *(const float4*)(A + (size_t)(m0 + m) * 256 + k0 + kq);
            As[kq + 0][m] = v.x; As[kq + 1][m] = v.y; As[kq + 2][m] = v.z; As[kq + 3][m] = v.w;
        }
#pragma unroll
        for (int p = 0; p < 4; ++p) { // B tile 32x128
            int f4 = tid + p * 256;
            int k = f4 >> 5, nq = (f4 & 31) * 4;
            *(float4*)&Bs[k][nq] = *(const float4*)(Bm + (size_t)(k0 + k) * 512 + n0 + nq);
        }
        __syncthreads();
#pragma unroll
        for (int k = 0; k < 32; ++k) {
            float4 a0 = *(const float4*)&As[k][ty * 4];
            float4 a1 = *(const float4*)&As[k][ty * 4 + 64];
            float4 b0 = *(const float4*)&Bs[k][tx * 4];
            float4 b1 = *(const float4*)&Bs[k][tx * 4 + 64];
            float am[2][4] = {{a0.x, a0.y, a0.z, a0.w}, {a1.x, a1.y, a1.z, a1.w}};
            float bn[2][4] = {{b0.x, b0.y, b0.z, b0.w}, {b1.x, b1.y, b1.z, b1.w}};
#pragma unroll
            for (int mh = 0; mh < 2; ++mh)
#pragma unroll
                for (int nh = 0; nh < 2; ++nh)
#pragma unroll
                    for (int i = 0; i < 4; ++i)
#pragma unroll
                        for (int j = 0; j < 4; ++j)
                            acc[mh][nh][i][j] = fmaf(am[mh][i], bn[nh][j], acc[mh][nh][i][j]);
        }
    }
#pragma unroll
    for (int mh = 0; mh < 2; ++mh)
#pragma unroll
        for (int i = 0; i < 4; ++i) {
            int m = m0 + mh * 64 + ty * 4 + i;
#pragma unroll
            for (int nh = 0; nh < 2; ++nh) {
                int n = n0 + nh * 64 + tx * 4;
                float4 v = {acc[mh][nh][i][0], acc[mh][nh][i][1], acc[mh][nh][i][2], acc[mh][nh][i][3]};
                if (n < 256) {
                    *(float4*)(h + (size_t)m * 256 + n) = v;
                } else {
                    int o = n - 256;
                    v.x = sigmoidf_(v.x + Hb[o + 0]);
                    v.y = sigmoidf_(v.y + Hb[o + 1]);
                    v.z = sigmoidf_(v.z + Hb[o + 2]);
                    v.w = sigmoidf_(v.w + Hb[o + 3]);
                    *(float4*)(gate + (size_t)m * 256 + o) = v;
                }
            }
        }
}

// ---------------- per-row a_src/a_dst: one wave per row ----------------
__global__ __launch_bounds__(256) void asrc_kernel(const float* __restrict__ h,
                                                   const float* __restrict__ Ws,
                                                   float* __restrict__ a_src,
                                                   float* __restrict__ a_dst) {
    const int row = blockIdx.x * 4 + (threadIdx.x >> 6);
    const int lane = threadIdx.x & 63;
    float4 h4 = ((const float4*)(h + (size_t)row * 256))[lane];
    float4 ws = ((const float4*)Ws)[lane];
    float4 wd = ((const float4*)(Ws + 256))[lane];
    float s1 = h4.x * ws.x + h4.y * ws.y + h4.z * ws.z + h4.w * ws.w;
    float s2 = h4.x * wd.x + h4.y * wd.y + h4.z * wd.z + h4.w * wd.w;
#pragma unroll
    for (int m = 32; m >= 1; m >>= 1) {
        s1 += __shfl_xor(s1, m, 64);
        s2 += __shfl_xor(s2, m, 64);
    }
    if (lane == 0) { a_src[row] = s1; a_dst[row] = s2; }
}

// ---------------- per-batch sum over rows of h (raw sums; /N at use) ----------------
__global__ __launch_bounds__(256) void mean_kernel(const float* __restrict__ h,
                                                   float* __restrict__ mean_h) {
    const int blk = blockIdx.x;        // B*32 blocks
    const int b = blk >> 5, part = blk & 31;
    const int d = threadIdx.x;
    float sum = 0.f;
    const float* base = h + ((size_t)b * Nc + part * 64) * 256 + d;
#pragma unroll 4
    for (int r = 0; r < 64; ++r) sum += base[(size_t)r * 256];
    atomicAdd(&mean_h[b * 256 + d], sum);
}

// ---------------- zero strictly-upper tiles of I_A_raw ----------------
__global__ __launch_bounds__(256) void fill_kernel(float* __restrict__ out2) {
    const int b = blockIdx.x & 7, ib = blockIdx.x >> 3;
    const int j0 = (ib + 1) * 32;
    if (j0 >= Nc) return;
    const int i0 = ib * 32;
    const int w4 = (Nc - j0) >> 2;
    const float4 z = make_float4(0.f, 0.f, 0.f, 0.f);
    for (int r = 0; r < 32; ++r) {
        float4* row = (float4*)(out2 + ((size_t)b * Nc + i0 + r) * Nc + j0);
        for (int jc = threadIdx.x; jc < w4; jc += 256) row[jc] = z;
    }
}

// ---------------- scores + I_A write + p=exp(s-1) + partial P@h (atomic combine) ----------------
constexpr int CHUNK = 8;
__global__ __launch_bounds__(256) void score_kernel(
    const int* __restrict__ adj, const float* __restrict__ h,
    const float* __restrict__ a_src, const float* __restrict__ a_dst,
    const float* __restrict__ bs_p, float* __restrict__ out2,
    float* __restrict__ accO, float* __restrict__ sArr) {
    __shared__ __align__(16) float4 sh_h4[32 * 64]; // 32 KB: h rows j0..j0+31
    __shared__ __align__(16) float pt[32][36];      // [jj][r], padded for banks+align
    __shared__ float sh_as[32];

    // decode block -> (b, ib, c)
    const int bid = blockIdx.x;
    const int b = bid & 7; // batch -> XCD affinity
    int t = bid >> 3;      // 0..287
    int g = 0;
    while (g < 7 && 4 * (g + 1) * (g + 2) <= t) ++g;
    const int r_ = t - 4 * g * (g + 1);
    const int ib = g * 8 + r_ / (g + 1);
    const int c = r_ % (g + 1);
    const int i0 = ib * 32;
    const int t0 = c * CHUNK;
    const int t1 = min(ib + 1, t0 + CHUNK);

    const int tid = threadIdx.x;
    const int lane = tid & 63;
    const int w = tid >> 6;
    const int jj_ = tid & 31;
    const int r0 = tid >> 5; // 0..7
    const float bsv = bs_p[0];

    if (tid < 32) sh_as[tid] = a_src[b * Nc + i0 + tid];
    __syncthreads(); // FIX R2: sh_as is read by all waves below

    float4 acc[8];
#pragma unroll
    for (int r = 0; r < 8; ++r) acc[r] = make_float4(0.f, 0.f, 0.f, 0.f);
    float sLoc[4] = {0.f, 0.f, 0.f, 0.f};

    for (int tt = t0; tt < t1; ++tt) {
        const int j0 = tt * 32;
        if (tt > t0) __syncthreads();
        { // stage h tile (32 rows x 256 f32)
            const float4* src = (const float4*)(h + ((size_t)b * Nc + j0) * 256);
#pragma unroll
            for (int p = 0; p < 8; ++p) sh_h4[tid + p * 256] = src[tid + p * 256];
        }
        { // scores + I_A + p
            const int j = j0 + jj_;
            const float adstj = a_dst[b * Nc + j];
#pragma unroll
            for (int q = 0; q < 4; ++q) {
                const int r = r0 + 8 * q;
                const int i = i0 + r;
                const int av = adj[((size_t)b * Nc + i) * Nc + j];
                float IA;
                if (j > i) IA = 0.f;
                else if (j == i) IA = 1.f;
                else IA = -sigmoidf_(sh_as[r] + adstj + bsv);
                out2[((size_t)b * Nc + i) * Nc + j] = IA;
                const float p = ((j <= i) && (av == 1)) ? expf(IA - 1.f) : 0.f;
                pt[jj_][r] = p;
                float ts = p;
#pragma unroll
                for (int d = 16; d >= 1; d >>= 1) ts += __shfl_xor(ts, d, 32);
                if (jj_ == 0) sLoc[q] += ts;
            }
        }
        __syncthreads();
        { // partial P@h: wave w owns rows w*8..w*8+7; lane covers d
#pragma unroll 4
            for (int jj = 0; jj < 32; ++jj) {
                const float4 h4 = sh_h4[jj * 64 + lane];
                const float4 pa = *(const float4*)&pt[jj][w * 8];
                const float4 pb = *(const float4*)&pt[jj][w * 8 + 4];
                acc[0].x = fmaf(pa.x, h4.x, acc[0].x); acc[0].y = fmaf(pa.x, h4.y, acc[0].y);
                acc[0].z = fmaf(pa.x, h4.z, acc[0].z); acc[0].w = fmaf(pa.x, h4.w, acc[0].w);
                acc[1].x = fmaf(pa.y, h4.x, acc[1].x); acc[1].y = fmaf(pa.y, h4.y, acc[1].y);
                acc[1].z = fmaf(pa.y, h4.z, acc[1].z); acc[1].w = fmaf(pa.y, h4.w, acc[1].w);
                acc[2].x = fmaf(pa.z, h4.x, acc[2].x); acc[2].y = fmaf(pa.z, h4.y, acc[2].y);
                acc[2].z = fmaf(pa.z, h4.z, acc[2].z); acc[2].w = fmaf(pa.z, h4.w, acc[2].w);
                acc[3].x = fmaf(pa.w, h4.x, acc[3].x); acc[3].y = fmaf(pa.w, h4.y, acc[3].y);
                acc[3].z = fmaf(pa.w, h4.z, acc[3].z); acc[3].w = fmaf(pa.w, h4.w, acc[3].w);
                acc[4].x = fmaf(pb.x, h4.x, acc[4].x); acc[4].y = fmaf(pb.x, h4.y, acc[4].y);
                acc[4].z = fmaf(pb.x, h4.z, acc[4].z); acc[4].w = fmaf(pb.x, h4.w, acc[4].w);
                acc[5].x = fmaf(pb.y, h4.x, acc[5].x); acc[5].y = fmaf(pb.y, h4.y, acc[5].y);
                acc[5].z = fmaf(pb.y, h4.z, acc[5].z); acc[5].w = fmaf(pb.y, h4.w, acc[5].w);
                acc[6].x = fmaf(pb.z, h4.x, acc[6].x); acc[6].y = fmaf(pb.z, h4.y, acc[6].y);
                acc[6].z = fmaf(pb.z, h4.z, acc[6].z); acc[6].w = fmaf(pb.z, h4.w, acc[6].w);
                acc[7].x = fmaf(pb.w, h4.x, acc[7].x); acc[7].y = fmaf(pb.w, h4.y, acc[7].y);
                acc[7].z = fmaf(pb.w, h4.z, acc[7].z); acc[7].w = fmaf(pb.w, h4.w, acc[7].w);
            }
        }
    }
    // combine: atomic add partial O and partial row sums
#pragma unroll
    for (int rr = 0; rr < 8; ++rr) {
        float* dst = accO + ((size_t)b * Nc + i0 + w * 8 + rr) * 256 + lane * 4;
        atomicAdd(dst + 0, acc[rr].x);
        atomicAdd(dst + 1, acc[rr].y);
        atomicAdd(dst + 2, acc[rr].z);
        atomicAdd(dst + 3, acc[rr].w);
    }
    if (jj_ == 0) {
#pragma unroll
        for (int q = 0; q < 4; ++q) atomicAdd(&sArr[b * Nc + i0 + r0 + 8 * q], sLoc[q]);
    }
}

// ---------------- epilogue: normalize / mean-fallback, +b, ELU, gate mix ----------------
__global__ __launch_bounds__(256) void epilogue_kernel(
    const float* __restrict__ gate, const float* __restrict__ feat,
    const float* __restrict__ bvec, const float* __restrict__ mean_h,
    const float* __restrict__ sArr, float* __restrict__ out1) {
    const int row = blockIdx.x * 4 + (threadIdx.x >> 6);
    const int lane = threadIdx.x & 63;
    const int b = row >> 11;
    const size_t g = (size_t)row * 256;
    const float s = sArr[row];
    float4 v;
    if (s == 0.f) {
        float4 mh = ((const float4*)(mean_h + b * 256))[lane];
        const float inv = 1.0f / Nc;
        v.x = mh.x * inv; v.y = mh.y * inv; v.z = mh.z * inv; v.w = mh.w * inv;
    } else {
        float4 a = ((const float4*)(out1 + g))[lane];
        const float inv = 1.0f / s;
        v.x = a.x * inv; v.y = a.y * inv; v.z = a.z * inv; v.w = a.w * inv;
    }
    const float4 b4 = ((const float4*)bvec)[lane];
    v.x += b4.x; v.y += b4.y; v.z += b4.z; v.w += b4.w;
    v.x = v.x > 0.f ? v.x : expf(v.x) - 1.f;
    v.y = v.y > 0.f ? v.y : expf(v.y) - 1.f;
    v.z = v.z > 0.f ? v.z : expf(v.z) - 1.f;
    v.w = v.w > 0.f ? v.w : expf(v.w) - 1.f;
    const float4 g4 = ((const float4*)(gate + g))[lane];
    const float4 f4 = ((const float4*)(feat + g))[lane];
    float4 o;
    o.x = g4.x * v.x + (1.f - g4.x) * f4.x;
    o.y = g4.y * v.y + (1.f - g4.y) * f4.y;
    o.z = g4.z * v.z + (1.f - g4.z) * f4.z;
    o.w = g4.w * v.w + (1.f - g4.w) * f4.w;
    ((float4*)(out1 + g))[lane] = o;
}

extern "C" void kernel_launch(void* const* d_in, const int* in_sizes, int n_in,
                              void* d_out, int out_size, void* d_ws, size_t ws_size,
                              hipStream_t stream) {
    const float* feat = (const float*)d_in[0];
    const int* adj = (const int*)d_in[1];
    const float* W = (const float*)d_in[2];
    const float* bvec = (const float*)d_in[3];
    const float* Ws = (const float*)d_in[4];
    const float* bs = (const float*)d_in[5];
    const float* Hw = (const float*)d_in[6];
    const float* Hb = (const float*)d_in[7];

    float* ws = (float*)d_ws;
    float* Bm = ws;                       // 131072
    float* h = Bm + 131072;               // 4194304
    float* gate = h + 4194304;            // 4194304
    float* a_src = gate + 4194304;        // 16384
    float* a_dst = a_src + 16384;         // 16384
    float* mean_h = a_dst + 16384;        // 2048
    float* sArr = mean_h + 2048;          // 16384

    float* out1 = (float*)d_out;
    float* out2 = out1 + (size_t)BN * 256;

    hipLaunchKernelGGL(pack_b_kernel, dim3(512), dim3(256), 0, stream, W, Hw, Bm);
    hipLaunchKernelGGL(gemm128_kernel, dim3(128, 4), dim3(256), 0, stream, feat, Bm, Hb, h, gate);
    hipLaunchKernelGGL(asrc_kernel, dim3(4096), dim3(256), 0, stream, h, Ws, a_src, a_dst);
    hipMemsetAsync(mean_h, 0, 2048 * sizeof(float), stream);
    hipLaunchKernelGGL(mean_kernel, dim3(256), dim3(256), 0, stream, h, mean_h);
    hipMemsetAsync(sArr, 0, (size_t)BN * sizeof(float), stream);
    hipMemsetAsync(out1, 0, (size_t)BN * 256 * sizeof(float), stream);
    hipLaunchKernelGGL(fill_kernel, dim3(512), dim3(256), 0, stream, out2);
    hipLaunchKernelGGL(score_kernel, dim3(2304), dim3(256), 0, stream,
                       adj, h, a_src, a_dst, bs, out2, out1, sArr);
    hipLaunchKernelGGL(epilogue_kernel, dim3(4096), dim3(256), 0, stream,
                       gate, feat, bvec, mean_h, sArr, out1);
}

// Round 4
// 454.824 us; speedup vs baseline: 1.5385x; 1.3582x over previous
//
#include <hip/hip_runtime.h>
#include <math.h>

constexpr int Bc = 8, Nc = 2048, Dc = 256;
constexpr int BN = Bc * Nc; // 16384

typedef __attribute__((ext_vector_type(8))) short short8;
typedef __attribute__((ext_vector_type(4))) float f32x4;

__device__ __forceinline__ float sigmoidf_(float x) { return 1.0f / (1.0f + expf(-x)); }

__device__ __forceinline__ unsigned short f2bf(float f) { // RNE fp32 -> bf16
    unsigned int u = __float_as_uint(f);
    u = (u + 0x7FFFu + ((u >> 16) & 1u)) >> 16;
    return (unsigned short)u;
}

// load an 8-elem bf16 fragment: elems 0..3 at base[0..3], elems 4..7 at base[16..19].
// k-slot permutation: slot(g16,e): e<4 -> k=g16*4+e ; e>=4 -> k=16+g16*4+(e-4).
// A and B both loaded this way => consistent pairing, any bijection is valid.
__device__ __forceinline__ short8 ld_frag(const unsigned short* base) {
    ushort4 lo = *(const ushort4*)(base);
    ushort4 hi = *(const ushort4*)(base + 16);
    short8 a;
    a[0] = (short)lo.x; a[1] = (short)lo.y; a[2] = (short)lo.z; a[3] = (short)lo.w;
    a[4] = (short)hi.x; a[5] = (short)hi.y; a[6] = (short)hi.z; a[7] = (short)hi.w;
    return a;
}

__device__ __forceinline__ f32x4 fz4() { f32x4 z = {0.f, 0.f, 0.f, 0.f}; return z; }

// ---------------- cast feat fp32 -> bf16 ----------------
__global__ __launch_bounds__(256) void cast_kernel(const float* __restrict__ f,
                                                   unsigned short* __restrict__ o) {
    int i = (blockIdx.x * 256 + threadIdx.x) * 4;
    float4 v = *(const float4*)(f + i);
    ushort4 u = {f2bf(v.x), f2bf(v.y), f2bf(v.z), f2bf(v.w)};
    *(ushort4*)(o + i) = u;
}

// ---------------- pack BmT[512 n][256 k] bf16 = [ W | Hw^T ]^T ----------------
__global__ __launch_bounds__(256) void pack_bt_kernel(const float* __restrict__ W,
                                                      const float* __restrict__ Hw,
                                                      unsigned short* __restrict__ BmT) {
    int idx = blockIdx.x * 256 + threadIdx.x; // 0..131071 ; BmT[o][k], o=idx>>8, k=idx&255
    int o = idx >> 8, k = idx & 255;
    float v = (o < 256) ? W[k * 256 + o] : Hw[(o - 256) * 256 + k];
    BmT[idx] = f2bf(v);
}

// ---------------- MFMA GEMM: C(16384x512) = featb @ BmT^T ; h | gate epilogue ----------------
// tile 64m x 128n, 4 waves (wave owns 32 n), no LDS: A from L1, B from L2.
__global__ __launch_bounds__(256) void gemm_mfma(const unsigned short* __restrict__ featb,
                                                 const unsigned short* __restrict__ BmT,
                                                 const float* __restrict__ Hb,
                                                 float* __restrict__ h,
                                                 float* __restrict__ gate) {
    const int tid = threadIdx.x, lane = tid & 63, w = tid >> 6;
    const int g16 = lane >> 4, li = lane & 15;
    const int m0 = blockIdx.x * 64, nw = blockIdx.y * 128 + w * 32;
    f32x4 acc[4][2];
#pragma unroll
    for (int rf = 0; rf < 4; ++rf)
#pragma unroll
        for (int cf = 0; cf < 2; ++cf) acc[rf][cf] = fz4();
    for (int k0 = 0; k0 < 256; k0 += 32) {
        short8 Af[4];
#pragma unroll
        for (int rf = 0; rf < 4; ++rf)
            Af[rf] = ld_frag(featb + (size_t)(m0 + rf * 16 + li) * 256 + k0 + g16 * 4);
#pragma unroll
        for (int cf = 0; cf < 2; ++cf) {
            short8 Bf = ld_frag(BmT + (size_t)(nw + cf * 16 + li) * 256 + k0 + g16 * 4);
#pragma unroll
            for (int rf = 0; rf < 4; ++rf)
                acc[rf][cf] = __builtin_amdgcn_mfma_f32_16x16x32_bf16(Af[rf], Bf, acc[rf][cf], 0, 0, 0);
        }
    }
#pragma unroll
    for (int rf = 0; rf < 4; ++rf)
#pragma unroll
        for (int cf = 0; cf < 2; ++cf) {
            const int n = nw + cf * 16 + li;
#pragma unroll
            for (int reg = 0; reg < 4; ++reg) {
                const int m = m0 + rf * 16 + g16 * 4 + reg;
                float v = acc[rf][cf][reg];
                if (n < 256) h[(size_t)m * 256 + n] = v;
                else gate[(size_t)m * 256 + (n - 256)] = sigmoidf_(v + Hb[n - 256]);
            }
        }
}

// ---------------- transpose-cast: h fp32 [b][j][d] -> hT bf16 [b][d][j] ----------------
__global__ __launch_bounds__(256) void tr64_kernel(const float* __restrict__ h,
                                                   unsigned short* __restrict__ hT) {
    __shared__ float tile[64][65];
    const int j0 = blockIdx.x * 64, d0 = blockIdx.y * 64, b = blockIdx.z;
    const int tid = threadIdx.x;
#pragma unroll
    for (int p = 0; p < 16; ++p) {
        int idx = tid + p * 256;
        int jl = idx >> 6, dl = idx & 63;
        tile[jl][dl] = h[((size_t)b * Nc + j0 + jl) * 256 + d0 + dl];
    }
    __syncthreads();
#pragma unroll
    for (int p = 0; p < 16; ++p) {
        int idx = tid + p * 256;
        int dl = idx >> 6, jl = idx & 63;
        hT[((size_t)b * 256 + d0 + dl) * Nc + j0 + jl] = f2bf(tile[jl][dl]);
    }
}

// ---------------- per-row a_src/a_dst (fp32 h) ----------------
__global__ __launch_bounds__(256) void asrc_kernel(const float* __restrict__ h,
                                                   const float* __restrict__ Ws,
                                                   float* __restrict__ a_src,
                                                   float* __restrict__ a_dst) {
    const int row = blockIdx.x * 4 + (threadIdx.x >> 6);
    const int lane = threadIdx.x & 63;
    float4 h4 = ((const float4*)(h + (size_t)row * 256))[lane];
    float4 ws = ((const float4*)Ws)[lane];
    float4 wd = ((const float4*)(Ws + 256))[lane];
    float s1 = h4.x * ws.x + h4.y * ws.y + h4.z * ws.z + h4.w * ws.w;
    float s2 = h4.x * wd.x + h4.y * wd.y + h4.z * wd.z + h4.w * wd.w;
#pragma unroll
    for (int m = 32; m >= 1; m >>= 1) {
        s1 += __shfl_xor(s1, m, 64);
        s2 += __shfl_xor(s2, m, 64);
    }
    if (lane == 0) { a_src[row] = s1; a_dst[row] = s2; }
}

// ---------------- per-batch sum over rows of h ----------------
__global__ __launch_bounds__(256) void mean_kernel(const float* __restrict__ h,
                                                   float* __restrict__ mean_h) {
    const int blk = blockIdx.x; // B*32
    const int b = blk >> 5, part = blk & 31;
    const int d = threadIdx.x;
    float sum = 0.f;
    const float* base = h + ((size_t)b * Nc + part * 64) * 256 + d;
#pragma unroll 4
    for (int r = 0; r < 64; ++r) sum += base[(size_t)r * 256];
    atomicAdd(&mean_h[b * 256 + d], sum);
}

// ---------------- scores + I_A write + MFMA P@h partials (atomic combine) ----------------
constexpr int CHUNK = 8;
__global__ __launch_bounds__(256) void score_mfma(
    const int* __restrict__ adj, const unsigned short* __restrict__ hT,
    const float* __restrict__ a_src, const float* __restrict__ a_dst,
    const float* __restrict__ bs_p, float* __restrict__ out2,
    float* __restrict__ accO, float* __restrict__ sArr) {
    __shared__ unsigned short pt[32][40]; // P tile bf16, [r][k], padded stride
    __shared__ float sh_as[32];

    const int bid = blockIdx.x;
    const int b = bid & 7; // batch -> XCD affinity
    int t = bid >> 3;      // 0..287
    int g = 0;
    while (g < 7 && 4 * (g + 1) * (g + 2) <= t) ++g;
    const int r_ = t - 4 * g * (g + 1);
    const int ib = g * 8 + r_ / (g + 1);
    const int c = r_ % (g + 1);
    const int i0 = ib * 32;
    const int t0 = c * CHUNK;
    const int t1 = min(ib + 1, t0 + CHUNK);

    const int tid = threadIdx.x;
    const int lane = tid & 63;
    const int w = tid >> 6;
    const int g16 = lane >> 4, li = lane & 15;
    const int jj_ = tid & 31;
    const int r0 = tid >> 5; // 0..7
    const float bsv = bs_p[0];

    if (tid < 32) sh_as[tid] = a_src[b * Nc + i0 + tid];
    __syncthreads();

    f32x4 acc[2][4]; // [rf][cf]
#pragma unroll
    for (int rf = 0; rf < 2; ++rf)
#pragma unroll
        for (int cf = 0; cf < 4; ++cf) acc[rf][cf] = fz4();
    f32x4 sacc0 = fz4(), sacc1 = fz4();
    short8 ones;
#pragma unroll
    for (int e = 0; e < 8; ++e) ones[e] = (short)0x3F80; // bf16 1.0

    const unsigned short* hTb = hT + (size_t)b * 256 * Nc;

    for (int tt = t0; tt < t1; ++tt) {
        const int j0 = tt * 32;
        if (tt > t0) __syncthreads(); // protect pt before overwrite
        { // score phase: p = exp(score-1) (fixed shift; exact after normalize)
            const int j = j0 + jj_;
            const float adstj = a_dst[b * Nc + j];
#pragma unroll
            for (int q = 0; q < 4; ++q) {
                const int r = r0 + 8 * q;
                const int i = i0 + r;
                const int av = adj[((size_t)b * Nc + i) * Nc + j];
                float IA, p;
                if (j > i) { IA = 0.f; p = 0.f; }
                else {
                    IA = (j == i) ? 1.f : -sigmoidf_(sh_as[r] + adstj + bsv);
                    out2[((size_t)b * Nc + i) * Nc + j] = IA; // upper tri from memset
                    p = (av == 1) ? expf(IA - 1.f) : 0.f;
                }
                pt[r][jj_] = f2bf(p);
            }
        }
        __syncthreads();
        { // MFMA phase: A = P rows (from LDS), B = h cols (from hT in L2)
            short8 A0 = ld_frag(&pt[li][g16 * 4]);
            short8 A1 = ld_frag(&pt[16 + li][g16 * 4]);
            if (w == 0) {
                sacc0 = __builtin_amdgcn_mfma_f32_16x16x32_bf16(A0, ones, sacc0, 0, 0, 0);
                sacc1 = __builtin_amdgcn_mfma_f32_16x16x32_bf16(A1, ones, sacc1, 0, 0, 0);
            }
#pragma unroll
            for (int cf = 0; cf < 4; ++cf) {
                const unsigned short* bp =
                    hTb + (size_t)(w * 64 + cf * 16 + li) * Nc + j0 + g16 * 4;
                short8 Bf = ld_frag(bp);
                acc[0][cf] = __builtin_amdgcn_mfma_f32_16x16x32_bf16(A0, Bf, acc[0][cf], 0, 0, 0);
                acc[1][cf] = __builtin_amdgcn_mfma_f32_16x16x32_bf16(A1, Bf, acc[1][cf], 0, 0, 0);
            }
        }
    }
    // combine partials
#pragma unroll
    for (int rf = 0; rf < 2; ++rf)
#pragma unroll
        for (int cf = 0; cf < 4; ++cf) {
            const int row = i0 + rf * 16 + g16 * 4;
            float* dst = accO + ((size_t)b * Nc + row) * 256 + w * 64 + cf * 16 + li;
#pragma unroll
            for (int reg = 0; reg < 4; ++reg)
                atomicAdd(dst + (size_t)reg * 256, acc[rf][cf][reg]);
        }
    if (w == 0 && li == 0) {
#pragma unroll
        for (int reg = 0; reg < 4; ++reg) {
            atomicAdd(&sArr[b * Nc + i0 + g16 * 4 + reg], sacc0[reg]);
            atomicAdd(&sArr[b * Nc + i0 + 16 + g16 * 4 + reg], sacc1[reg]);
        }
    }
}

// ---------------- epilogue: normalize / mean-fallback, +b, ELU, gate mix ----------------
__global__ __launch_bounds__(256) void epilogue_kernel(
    const float* __restrict__ gate, const float* __restrict__ feat,
    const float* __restrict__ bvec, const float* __restrict__ mean_h,
    const float* __restrict__ sArr, float* __restrict__ out1) {
    const int row = blockIdx.x * 4 + (threadIdx.x >> 6);
    const int lane = threadIdx.x & 63;
    const int b = row >> 11;
    const size_t g = (size_t)row * 256;
    const float s = sArr[row];
    float4 v;
    if (s == 0.f) { // fully-masked row: softmax uniform over ALL N cols
        float4 mh = ((const float4*)(mean_h + b * 256))[lane];
        const float inv = 1.0f / Nc;
        v.x = mh.x * inv; v.y = mh.y * inv; v.z = mh.z * inv; v.w = mh.w * inv;
    } else {
        float4 a = ((const float4*)(out1 + g))[lane];
        const float inv = 1.0f / s;
        v.x = a.x * inv; v.y = a.y * inv; v.z = a.z * inv; v.w = a.w * inv;
    }
    const float4 b4 = ((const float4*)bvec)[lane];
    v.x += b4.x; v.y += b4.y; v.z += b4.z; v.w += b4.w;
    v.x = v.x > 0.f ? v.x : expf(v.x) - 1.f;
    v.y = v.y > 0.f ? v.y : expf(v.y) - 1.f;
    v.z = v.z > 0.f ? v.z : expf(v.z) - 1.f;
    v.w = v.w > 0.f ? v.w : expf(v.w) - 1.f;
    const float4 g4 = ((const float4*)(gate + g))[lane];
    const float4 f4 = ((const float4*)(feat + g))[lane];
    float4 o;
    o.x = g4.x * v.x + (1.f - g4.x) * f4.x;
    o.y = g4.y * v.y + (1.f - g4.y) * f4.y;
    o.z = g4.z * v.z + (1.f - g4.z) * f4.z;
    o.w = g4.w * v.w + (1.f - g4.w) * f4.w;
    ((float4*)(out1 + g))[lane] = o;
}

extern "C" void kernel_launch(void* const* d_in, const int* in_sizes, int n_in,
                              void* d_out, int out_size, void* d_ws, size_t ws_size,
                              hipStream_t stream) {
    const float* feat = (const float*)d_in[0];
    const int* adj = (const int*)d_in[1];
    const float* W = (const float*)d_in[2];
    const float* bvec = (const float*)d_in[3];
    const float* Ws = (const float*)d_in[4];
    const float* bs = (const float*)d_in[5];
    const float* Hw = (const float*)d_in[6];
    const float* Hb = (const float*)d_in[7];

    float* ws = (float*)d_ws;
    // featb (bf16, 16384x256) reused as hT (bf16, 8x256x2048) after gemm+transpose
    unsigned short* featb = (unsigned short*)ws;            // 4,194,304 ushort = 2,097,152 f
    unsigned short* hT = featb;                              // same buffer, later lifetime
    unsigned short* BmT = featb + 4194304;                   // 131,072 ushort = 65,536 f
    float* h = ws + 2097152 + 65536;                         // 4,194,304 f
    float* gate = h + 4194304;                               // 4,194,304 f
    float* a_src = gate + 4194304;                           // 16384
    float* a_dst = a_src + 16384;                            // 16384
    float* mean_h = a_dst + 16384;                           // 2048
    float* sArr = mean_h + 2048;                             // 16384

    float* out1 = (float*)d_out;
    float* out2 = out1 + (size_t)BN * 256;

    hipLaunchKernelGGL(cast_kernel, dim3(4096), dim3(256), 0, stream, feat, featb);
    hipLaunchKernelGGL(pack_bt_kernel, dim3(512), dim3(256), 0, stream, W, Hw, BmT);
    hipLaunchKernelGGL(gemm_mfma, dim3(256, 4), dim3(256), 0, stream, featb, BmT, Hb, h, gate);
    hipLaunchKernelGGL(tr64_kernel, dim3(32, 4, 8), dim3(256), 0, stream, h, hT);
    hipLaunchKernelGGL(asrc_kernel, dim3(4096), dim3(256), 0, stream, h, Ws, a_src, a_dst);
    hipMemsetAsync(mean_h, 0, 2048 * sizeof(float), stream);
    hipLaunchKernelGGL(mean_kernel, dim3(256), dim3(256), 0, stream, h, mean_h);
    hipMemsetAsync(sArr, 0, (size_t)BN * sizeof(float), stream);
    hipMemsetAsync(out1, 0, (size_t)BN * 256 * sizeof(float), stream);
    hipMemsetAsync(out2, 0, (size_t)BN * (size_t)Nc * sizeof(float), stream);
    hipLaunchKernelGGL(score_mfma, dim3(2304), dim3(256), 0, stream,
                       adj, hT, a_src, a_dst, bs, out2, out1, sArr);
    hipLaunchKernelGGL(epilogue_kernel, dim3(4096), dim3(256), 0, stream,
                       gate, feat, bvec, mean_h, sArr, out1);
}